// Round 4
// baseline (1058.961 us; speedup 1.0000x reference)
//
#include <hip/hip_runtime.h>
#include <hip/hip_bf16.h>
#include <hip/hip_cooperative_groups.h>
#include <cstdint>

namespace cg = cooperative_groups;

// Problem constants
#define BB 16
#define NN 4096
#define MM 1024
#define KNB 16
#define CIN 64
#define COUT 128
#define RTOT (BB*MM*KNB)   // 262144 rows
#define AP1 104            // gemm1 LDS row stride (96 used + 8 pad), bf16
#define AP2 136            // gemm2 LDS row stride (128 + 8 pad), bf16

typedef __attribute__((ext_vector_type(8))) short short8v;
typedef __attribute__((ext_vector_type(4))) float floatx4;
typedef __attribute__((ext_vector_type(2))) float f32x2;
typedef __attribute__((ext_vector_type(2))) unsigned int uint2v;

// ---------- helpers ----------
__device__ __forceinline__ float bflo(uint32_t u){ return __uint_as_float(u << 16); }
__device__ __forceinline__ float bfhi(uint32_t u){ return __uint_as_float(u & 0xffff0000u); }
__device__ __forceinline__ uint32_t f2bf_pk(float a, float b){
  uint32_t ua = __float_as_uint(a), ub = __float_as_uint(b);
  ua += 0x7fffu + ((ua >> 16) & 1u);   // RNE
  ub += 0x7fffu + ((ub >> 16) & 1u);
  return (ua >> 16) | (ub & 0xffff0000u);
}
__device__ __forceinline__ uint16_t f2bf1(float a){
  uint32_t u = __float_as_uint(a);
  u += 0x7fffu + ((u >> 16) & 1u);
  return (uint16_t)(u >> 16);
}
template<int CTRL>
__device__ __forceinline__ float dpp_f(float v){
  return __int_as_float(__builtin_amdgcn_update_dpp(__float_as_int(v), __float_as_int(v), CTRL, 0xf, 0xf, false));
}
// all-VALU cross-row max combine (gfx950 permlane swaps); fallback to DS pipe
__device__ __forceinline__ float plmax16(float v){
#if __has_builtin(__builtin_amdgcn_permlane16_swap)
  uint2v r = __builtin_amdgcn_permlane16_swap(__float_as_uint(v), __float_as_uint(v), false, false);
  return fmaxf(__uint_as_float(r[0]), __uint_as_float(r[1]));
#else
  return fmaxf(v, __int_as_float(__builtin_amdgcn_ds_swizzle(__float_as_int(v), 0x401F)));
#endif
}
__device__ __forceinline__ float plmax32(float v){
#if __has_builtin(__builtin_amdgcn_permlane32_swap)
  uint2v r = __builtin_amdgcn_permlane32_swap(__float_as_uint(v), __float_as_uint(v), false, false);
  return fmaxf(__uint_as_float(r[0]), __uint_as_float(r[1]));
#else
  return fmaxf(v, __shfl_xor(v, 32));
#endif
}

// ---------- LDS ----------
// Exchange payload per wave: 32B = {key_lo, key_hi, x_bits, y_bits} + {z_bits, pad...}
struct FpsS { float4 pcv[NN]; float4 sel[MM]; uint4 pay[2][4][2]; };      // 82176 B
struct TrS  { float t[64][65]; };                                         // 16640 B
struct ConsS{ uint16_t Bh1[128*AP1]; uint16_t AhD[128*AP2];
              int winq[8*16]; float ssum[128]; float ssq[128]; };         // 62976 B
union PreU  { FpsS fps; TrS tr; ConsS cons; };

// ================= K1: FPS producer (blocks 0-15) || prework + pipelined kNN+GEMM1
//                       consumers (blocks 16-255) =================
// Producer v5: barrier exchange (R2 structure, measured best) + COORDS-IN-PAYLOAD:
// the li-selection chain also carries (x,y,z) of the lane's best point; lane fl's
// coords are readlane'd into the 32B exchange payload {key,x,y,z}. The merge selects
// coords with the same 3 u64-key compares -> the dependent pcv[midx] LDS read is
// GONE from the serial chain. sel[i] written by all 4 FPS waves' lane 0 (same
// addr/data) to remove wave-0 skew. Selection arithmetic bit-identical to v2-v4.
__global__ __launch_bounds__(512, 2) void k_pre2(
    const float* __restrict__ p1, const float* __restrict__ x1,
    const float* __restrict__ w1,
    float* __restrict__ outp2, float* __restrict__ p2w,
    float4* __restrict__ p1n, uint16_t* __restrict__ xtb, float* __restrict__ Sz,
    uint16_t* __restrict__ h1, float* __restrict__ S1,
    int* __restrict__ prog, int* __restrict__ prep_done)
{
  __shared__ PreU u;
  const int blk = blockIdx.x, tid = threadIdx.x;
  const int lane = tid & 63, wid = tid >> 6;

  if (blk < 16){
    // ---------------- FPS producer ----------------
    int b = blk;
    const float* pb = p1 + (size_t)b*NN*3;
    {
      float4 f[6];
      const float4* src = (const float4*)(pb + tid*24);
      #pragma unroll
      for (int j=0;j<6;j++) f[j] = src[j];
      const float* fa = (const float*)f;
      #pragma unroll
      for (int j=0;j<8;j++)
        u.fps.pcv[tid*8 + j] = make_float4(fa[3*j], fa[3*j+1], fa[3*j+2], 0.f);
    }
    __syncthreads();                                   // B0: pcv staged
    float4 c00 = u.fps.pcv[0];
    float cx = c00.x, cy = c00.y, cz = c00.z;
    if (tid==0) u.fps.sel[0] = make_float4(cx, cy, cz, 0.f);

    // per-lane state: 16 consecutive points (lane-major ascending = global idx order)
    f32x2 px2[8] = {}, py2[8] = {}, pz2[8] = {}, ds2[8] = {};
    const int g0 = tid*16;
    if (wid < 4){
      #pragma unroll
      for (int j=0;j<8;j++){
        float4 a = u.fps.pcv[g0 + 2*j];
        float4 bq = u.fps.pcv[g0 + 2*j + 1];
        px2[j][0]=a.x; px2[j][1]=bq.x;
        py2[j][0]=a.y; py2[j][1]=bq.y;
        pz2[j][0]=a.z; pz2[j][1]=bq.z;
        ds2[j][0]=1e10f; ds2[j][1]=1e10f;
      }
    }
    __syncthreads();                                   // B1: state loaded

    for (int i=1;i<MM;i++){
      if (wid < 4){
        {
          #pragma clang fp contract(off)
          f32x2 cx2; cx2[0]=cx; cx2[1]=cx;
          f32x2 cy2; cy2[0]=cy; cy2[1]=cy;
          f32x2 cz2; cz2[0]=cz; cz2[1]=cz;
          #pragma unroll
          for (int j=0;j<8;j++){
            f32x2 dx = px2[j] - cx2;
            f32x2 dy = py2[j] - cy2;
            f32x2 dz = pz2[j] - cz2;
            f32x2 d  = dx*dx + dy*dy + dz*dz;   // ((x^2+y^2)+z^2), RN, no fma
            ds2[j] = __builtin_elementwise_min(ds2[j], d);
          }
        }
        // lane-local max (pk tree)
        f32x2 t0 = __builtin_elementwise_max(ds2[0], ds2[1]);
        f32x2 t1 = __builtin_elementwise_max(ds2[2], ds2[3]);
        f32x2 t2 = __builtin_elementwise_max(ds2[4], ds2[5]);
        f32x2 t3 = __builtin_elementwise_max(ds2[6], ds2[7]);
        f32x2 u0 = __builtin_elementwise_max(t0, t1);
        f32x2 u1 = __builtin_elementwise_max(t2, t3);
        f32x2 vv = __builtin_elementwise_max(u0, u1);
        float lm = fmaxf(vv[0], vv[1]);
        // first local index attaining lm, carrying coords (descending overwrite -> smallest wins)
        int li = g0 + 15;
        float bx = px2[7][1], by = py2[7][1], bz = pz2[7][1];
        #pragma unroll
        for (int j=14;j>=0;j--){
          bool t = (ds2[j>>1][j & 1] == lm);
          li = t ? (g0 + j) : li;
          bx = t ? px2[j>>1][j & 1] : bx;
          by = t ? py2[j>>1][j & 1] : by;
          bz = t ? pz2[j>>1][j & 1] : bz;
        }
        // wave max, all-VALU: 4 DPP row steps + permlane16/32 swaps
        float wm = lm;
        wm = fmaxf(wm, dpp_f<0xB1>(wm));    // quad xor1
        wm = fmaxf(wm, dpp_f<0x4E>(wm));    // quad xor2
        wm = fmaxf(wm, dpp_f<0x124>(wm));   // row_ror:4
        wm = fmaxf(wm, dpp_f<0x128>(wm));   // row_ror:8
        wm = plmax16(wm);
        wm = plmax32(wm);
        // first lane holding the max -> its index + coords
        unsigned long long bmask = __ballot(lm == wm);
        int fl = (int)__builtin_ctzll(bmask);
        int wi = __builtin_amdgcn_readlane(li, fl);
        unsigned xb = (unsigned)__builtin_amdgcn_readlane(__float_as_int(bx), fl);
        unsigned yb = (unsigned)__builtin_amdgcn_readlane(__float_as_int(by), fl);
        unsigned zb = (unsigned)__builtin_amdgcn_readlane(__float_as_int(bz), fl);
        if (lane == 0){
          unsigned long long key = (((unsigned long long)(unsigned)__float_as_uint(wm)) << 32)
                                 | (0xFFFu ^ (unsigned)wi);
          uint4* slot = &u.fps.pay[i&1][wid][0];
          slot[0] = make_uint4((unsigned)key, (unsigned)(key>>32), xb, yb);
          slot[1] = make_uint4(zb, 0u, 0u, 0u);
        }
      }
      __syncthreads();
      if (wid < 4){
        const uint4* P = &u.fps.pay[i&1][0][0];
        uint4 a0=P[0], e0=P[1], a1=P[2], e1=P[3], a2=P[4], e2=P[5], a3=P[6], e3=P[7];
        unsigned long long k0 = (((unsigned long long)a0.y)<<32)|a0.x;
        unsigned long long k1 = (((unsigned long long)a1.y)<<32)|a1.x;
        unsigned long long k2 = (((unsigned long long)a2.y)<<32)|a2.x;
        unsigned long long k3 = (((unsigned long long)a3.y)<<32)|a3.x;
        bool c01 = k1 > k0, c23 = k3 > k2;
        unsigned long long k01 = c01?k1:k0, k23 = c23?k3:k2;
        unsigned x01 = c01?a1.z:a0.z, y01 = c01?a1.w:a0.w, z01 = c01?e1.x:e0.x;
        unsigned x23 = c23?a3.z:a2.z, y23 = c23?a3.w:a2.w, z23 = c23?e3.x:e2.x;
        bool cf = k23 > k01;
        cx = __uint_as_float(cf?x23:x01);
        cy = __uint_as_float(cf?y23:y01);
        cz = __uint_as_float(cf?z23:z01);
        if (lane == 0) u.fps.sel[i] = make_float4(cx, cy, cz, 0.f);
      } else if (wid == 4 && (i & 63) == 0){
        // flush previous 64 selections (sel[e] for e<=i-1 written pre-barrier_i)
        int e = i - 64 + lane;
        float4 s = u.fps.sel[e];
        float n2 = __fadd_rn(__fadd_rn(__fmul_rn(s.x,s.x),__fmul_rn(s.y,s.y)),__fmul_rn(s.z,s.z));
        *(float4*)(p2w + ((size_t)b*MM + e)*4) = make_float4(s.x, s.y, s.z, n2);
        if (lane == 0)
          __hip_atomic_store(&prog[b*16], i, __ATOMIC_RELEASE, __HIP_MEMORY_SCOPE_AGENT);
      }
    }
    __syncthreads();                                   // B_final
    if (wid == 4){
      int e = 960 + lane;
      float4 s = u.fps.sel[e];
      float n2 = __fadd_rn(__fadd_rn(__fmul_rn(s.x,s.x),__fmul_rn(s.y,s.y)),__fmul_rn(s.z,s.z));
      *(float4*)(p2w + ((size_t)b*MM + e)*4) = make_float4(s.x, s.y, s.z, n2);
      if (lane == 0)
        __hip_atomic_store(&prog[b*16], MM, __ATOMIC_RELEASE, __HIP_MEMORY_SCOPE_AGENT);
    }
    for (int e = tid; e < MM; e += 512){
      float4 s = u.fps.sel[e];
      float* o = outp2 + ((size_t)b*MM + e)*3;
      o[0]=s.x; o[1]=s.y; o[2]=s.z;
    }
  } else {
    // ---------------- prework ----------------
    for (int i = (blk-16)*512 + tid; i < 16384; i += 240*512) Sz[i] = 0.f;
    for (int i = (blk-16)*512 + tid; i < BB*NN; i += 240*512){
      float x = p1[(size_t)i*3+0], y = p1[(size_t)i*3+1], z = p1[(size_t)i*3+2];
      float n = __fadd_rn(__fadd_rn(__fmul_rn(x,x),__fmul_rn(y,y)),__fmul_rn(z,z));
      p1n[i] = make_float4(x,y,z,n);
    }
    for (int tile = blk-16; tile < 1024; tile += 240){
      int b = tile >> 6, n0 = (tile & 63)*64;
      __syncthreads();
      int c = tid >> 3, q = tid & 7;
      const float* src = x1 + ((size_t)(b*64 + c))*NN + n0 + q*8;
      float4 f0 = *(const float4*)src, f1 = *(const float4*)(src+4);
      u.tr.t[c][q*8+0]=f0.x; u.tr.t[c][q*8+1]=f0.y; u.tr.t[c][q*8+2]=f0.z; u.tr.t[c][q*8+3]=f0.w;
      u.tr.t[c][q*8+4]=f1.x; u.tr.t[c][q*8+5]=f1.y; u.tr.t[c][q*8+6]=f1.z; u.tr.t[c][q*8+7]=f1.w;
      __syncthreads();
      int n = tid >> 3;
      uint32_t* dst = (uint32_t*)(xtb + ((size_t)(b*NN + n0 + n))*64 + q*8);
      #pragma unroll
      for (int j=0;j<4;j++)
        dst[j] = f2bf_pk(u.tr.t[q*8+2*j][n], u.tr.t[q*8+2*j+1][n]);
    }
    __threadfence();
    __syncthreads();
    if (tid == 0) atomicAdd(prep_done, 1);
    // stage w1 -> Bh1 (K-perm [x(64)|rel(3)|0]); zero block stats (TrS dead; union switch)
    for (int e = tid; e < 128*96; e += 512){
      int o = e / 96, k = e - o*96;
      float v = (k < 64) ? w1[o*67 + 3 + k] : ((k < 67) ? w1[o*67 + (k-64)] : 0.f);
      u.cons.Bh1[o*AP1 + k] = f2bf1(v);
    }
    if (tid < 128){ u.cons.ssum[tid]=0.f; u.cons.ssq[tid]=0.f; }
    __syncthreads();
    // wait for all 240 prework blocks (p1n/xtb from other blocks)
    {
      int pv = 0, sp = 0;
      if (lane == 0) pv = __hip_atomic_load(prep_done, __ATOMIC_ACQUIRE, __HIP_MEMORY_SCOPE_AGENT);
      pv = __shfl(pv, 0);
      while (pv < 240 && sp < (1<<16)){
        __builtin_amdgcn_s_sleep(64);
        if (lane == 0) pv = __hip_atomic_load(prep_done, __ATOMIC_ACQUIRE, __HIP_MEMORY_SCOPE_AGENT);
        pv = __shfl(pv, 0); sp++;
      }
    }
    // ---------------- pipelined kNN + fused GEMM1, one query per wave-step ----------------
    int ml = lane & 15, quad = lane >> 4, seg = lane >> 4;
    int gw = (blk-16)*8 + wid;                 // [0,1920)
    for (int qi = gw; qi < BB*MM; qi += 1920){
      int b = qi & 15, m = qi >> 4;
      int q2 = b*MM + m;
      // wait for centroid m (acquire; 1.7us-granularity sleep to cut line contention)
      {
        int pv = 0, sp = 0;
        if (lane == 0) pv = __hip_atomic_load(&prog[b*16], __ATOMIC_ACQUIRE, __HIP_MEMORY_SCOPE_AGENT);
        pv = __shfl(pv, 0);
        while (pv <= m && sp < (1<<16)){
          __builtin_amdgcn_s_sleep(64);
          if (lane == 0) pv = __hip_atomic_load(&prog[b*16], __ATOMIC_ACQUIRE, __HIP_MEMORY_SCOPE_AGENT);
          pv = __shfl(pv, 0); sp++;
        }
      }
      const float4 qv = *(const float4*)(p2w + (size_t)q2*4);
      const float4* pbn = p1n + (size_t)b*NN;
      float bd[16]; int bi[16];
      #pragma unroll
      for (int s=0;s<16;s++){ bd[s] = 1e30f; bi[s] = 0; }
      float wv = 1e30f; int wslot = 0;

      #define KPROC(T, PV) { \
        float dot = fmaf(qv.z, (PV).z, fmaf(qv.y, (PV).y, __fmul_rn(qv.x, (PV).x))); \
        float d2 = __fsub_rn(__fadd_rn(qv.w, (PV).w), __fmul_rn(2.0f, dot)); \
        if (d2 < wv){ \
          int c = (T)*64 + lane; \
          _Pragma("unroll") \
          for (int s=0;s<16;s++) if (s==wslot){ bd[s]=d2; bi[s]=c; } \
          wv = bd[0]; wslot = 0; \
          _Pragma("unroll") \
          for (int s=1;s<16;s++) if (bd[s] > wv){ wv = bd[s]; wslot = s; } \
        } }

      float4 cur = pbn[lane];
      for (int t=0;t<63;t++){
        float4 nx = pbn[(t+1)*64 + lane];
        KPROC(t, cur);
        cur = nx;
      }
      KPROC(63, cur);
      #undef KPROC

      float lv = bd[0]; int ls = 0;
      #pragma unroll
      for (int s=1;s<16;s++) if (bd[s] < lv){ lv = bd[s]; ls = s; }
      for (int r=0;r<16;r++){
        float rv = lv; int rl = lane;
        #pragma unroll
        for (int off=32; off>=1; off>>=1){
          float ov = __shfl_xor(rv, off); int ol = __shfl_xor(rl, off);
          if (ov < rv || (ov == rv && ol < rl)){ rv = ov; rl = ol; }
        }
        if (lane == rl){
          int idx = 0;
          #pragma unroll
          for (int s=0;s<16;s++) if (s==ls) idx = bi[s];
          u.cons.winq[wid*16 + r] = idx;
          #pragma unroll
          for (int s=0;s<16;s++) if (s==ls) bd[s] = 1e30f;
          lv = bd[0]; ls = 0;
          #pragma unroll
          for (int s=1;s<16;s++) if (bd[s] < lv){ lv = bd[s]; ls = s; }
        }
      }
      // ---- fused GEMM1 for this query's 16 rows (wave-private LDS rows) ----
      int n = u.cons.winq[wid*16 + ml];        // same-wave DS order: winq writes done
      {
        const uint4* s4 = (const uint4*)(xtb + ((size_t)(b*NN + n))*64 + seg*16);
        uint4* d4 = (uint4*)(u.cons.AhD + (wid*16 + ml)*AP2 + seg*16);
        d4[0] = s4[0]; d4[1] = s4[1];
        if (seg == 0){
          const float* pp = p1 + ((size_t)(b*NN + n))*3;
          float rx = __fsub_rn(pp[0], qv.x);
          float ry = __fsub_rn(pp[1], qv.y);
          float rz = __fsub_rn(pp[2], qv.z);
          uint4* dr = (uint4*)(u.cons.AhD + (wid*16 + ml)*AP2 + 64);
          dr[0] = make_uint4(f2bf_pk(rx, ry), f2bf_pk(rz, 0.f), 0u, 0u);
          dr[1] = make_uint4(0u,0u,0u,0u);
          dr[2] = make_uint4(0u,0u,0u,0u);
          dr[3] = make_uint4(0u,0u,0u,0u);
        }
      }
      short8v af[3];
      #pragma unroll
      for (int kc=0;kc<3;kc++)
        af[kc] = *(const short8v*)(u.cons.AhD + (wid*16 + ml)*AP2 + kc*32 + quad*8);
      floatx4 acc[8];
      #pragma unroll
      for (int ct=0;ct<8;ct++) acc[ct] = (floatx4){0.f,0.f,0.f,0.f};
      #pragma unroll
      for (int ct=0;ct<8;ct++){
        #pragma unroll
        for (int kc=0;kc<3;kc++){
          short8v bf = *(const short8v*)(u.cons.Bh1 + (ct*16+ml)*AP1 + kc*32 + quad*8);
          acc[ct] = __builtin_amdgcn_mfma_f32_16x16x32_bf16(af[kc], bf, acc[ct], 0, 0, 0);
        }
      }
      float csum[8], csq[8];
      #pragma unroll
      for (int ct=0;ct<8;ct++){
        float a0=acc[ct][0], a1=acc[ct][1], a2=acc[ct][2], a3=acc[ct][3];
        float s = (a0+a1)+(a2+a3);
        float qq2 = (a0*a0+a1*a1)+(a2*a2+a3*a3);
        s += __shfl_xor(s,16);  s += __shfl_xor(s,32);
        qq2 += __shfl_xor(qq2,16); qq2 += __shfl_xor(qq2,32);
        csum[ct]=s; csq[ct]=qq2;
        #pragma unroll
        for (int r=0;r<4;r++)
          u.cons.AhD[(wid*16 + quad*4 + r)*AP2 + ct*16 + ml] = f2bf1(acc[ct][r]);
      }
      #pragma unroll
      for (int jj=0;jj<2;jj++){
        int ct = quad*2 + jj, col = ct*16 + ml;
        atomicAdd(&u.cons.ssum[col], csum[ct]);
        atomicAdd(&u.cons.ssq[col],  csq[ct]);
      }
      // coalesced h1 write of own 16 rows (reads after same-wave D writes)
      {
        const uint4* s4 = (const uint4*)(u.cons.AhD + (wid*16 + ml)*AP2 + seg*32);
        uint4* dst = (uint4*)(h1 + ((size_t)q2*16 + ml)*128 + seg*32);
        dst[0]=s4[0]; dst[1]=s4[1]; dst[2]=s4[2]; dst[3]=s4[3];
      }
    }
    __syncthreads();
    int cp = (blk & 31)*256;
    if (tid < 128){ atomicAdd(&S1[cp+tid], u.cons.ssum[tid]); atomicAdd(&S1[cp+128+tid], u.cons.ssq[tid]); }
  }
}

// ---------- K6: GEMM2 bf16 MFMA + fused k-pool extrema, persistent: 4 tiles/block ----------
__global__ __launch_bounds__(256) void k_gemm2(const __hip_bfloat16* __restrict__ h1,
                                               const float* __restrict__ w2,
                                               const float* __restrict__ g1v, const float* __restrict__ b1v,
                                               const float* __restrict__ S1, float* __restrict__ S2,
                                               float* __restrict__ hmax, float* __restrict__ hmin){
  __shared__ __hip_bfloat16 Ah[64*AP2];
  __shared__ __hip_bfloat16 Bh[128*AP2];
  __shared__ float scb[128], shb[128], ssum[128], ssq[128];
  int tid = threadIdx.x;
  if (tid < 128){
    float s=0.f, q=0.f;
    for (int c=0;c<32;c++){ s += S1[c*256+tid]; q += S1[c*256+128+tid]; }
    float inv = 1.0f / (float)RTOT;
    float mean = s * inv;
    float var  = q * inv - mean*mean;
    float rs = 1.0f / sqrtf(var + 1e-5f);
    float scv = g1v[tid] * rs;
    scb[tid] = scv;
    shb[tid] = b1v[tid] - mean*scv;
    ssum[tid] = 0.f; ssq[tid] = 0.f;
  }
  {
    int o = tid >> 1, hf = tid & 1;
    const float4* wr = (const float4*)(w2 + (size_t)o*128 + hf*64);
    uint32_t* bd = (uint32_t*)(Bh + o*AP2 + hf*64);
    #pragma unroll
    for (int q=0;q<16;q++){
      float4 v = wr[q];
      bd[2*q]   = f2bf_pk(v.x, v.y);
      bd[2*q+1] = f2bf_pk(v.z, v.w);
    }
  }
  __syncthreads();
  int lane = tid & 63, wid = tid >> 6;
  int m0 = wid*16, ml = lane & 15, quad = lane >> 4;
  for (int j = 0; j < 4; j++){
    int tile = blockIdx.x*4 + j;
    int r0 = tile * 64;
    if (j) __syncthreads();
    {
      int row = tid >> 2, seg = tid & 3;
      const uint4* hp4 = (const uint4*)(h1 + ((size_t)(r0+row))*128 + seg*32);
      #pragma unroll
      for (int q=0;q<4;q++){
        uint4 u = hp4[q];
        int cg = seg*32 + q*8;
        uint32_t wv[4] = {u.x,u.y,u.z,u.w};
        uint32_t ov[4];
        #pragma unroll
        for (int t=0;t<4;t++){
          int c = cg + t*2;
          float a0 = fmaxf(fmaf(bflo(wv[t]), scb[c],   shb[c]),   0.f);
          float a1 = fmaxf(fmaf(bfhi(wv[t]), scb[c+1], shb[c+1]), 0.f);
          ov[t] = f2bf_pk(a0, a1);
        }
        *(uint4*)(Ah + row*AP2 + cg) = make_uint4(ov[0],ov[1],ov[2],ov[3]);
      }
    }
    __syncthreads();
    short8v af[4];
    #pragma unroll
    for (int kc=0;kc<4;kc++)
      af[kc] = *(const short8v*)(Ah + (m0+ml)*AP2 + kc*32 + quad*8);
    floatx4 acc[8];
    #pragma unroll
    for (int ct=0;ct<8;ct++) acc[ct] = (floatx4){0.f,0.f,0.f,0.f};
    #pragma unroll
    for (int ct=0;ct<8;ct++){
      #pragma unroll
      for (int kc=0;kc<4;kc++){
        short8v bf = *(const short8v*)(Bh + (ct*16+ml)*AP2 + kc*32 + quad*8);
        acc[ct] = __builtin_amdgcn_mfma_f32_16x16x32_bf16(af[kc], bf, acc[ct], 0, 0, 0);
      }
    }
    int mrow = (r0 >> 4) + wid;
    float cm[8], cn[8], cs[8], cq[8];
    #pragma unroll
    for (int ct=0;ct<8;ct++){
      float a0=acc[ct][0], a1=acc[ct][1], a2=acc[ct][2], a3=acc[ct][3];
      float mx = fmaxf(fmaxf(a0,a1), fmaxf(a2,a3));
      float mn = fminf(fminf(a0,a1), fminf(a2,a3));
      float s  = (a0+a1)+(a2+a3);
      float q2 = (a0*a0+a1*a1)+(a2*a2+a3*a3);
      mx = fmaxf(mx, __shfl_xor(mx,16)); mx = fmaxf(mx, __shfl_xor(mx,32));
      mn = fminf(mn, __shfl_xor(mn,16)); mn = fminf(mn, __shfl_xor(mn,32));
      s += __shfl_xor(s,16);  s += __shfl_xor(s,32);
      q2 += __shfl_xor(q2,16); q2 += __shfl_xor(q2,32);
      cm[ct]=mx; cn[ct]=mn; cs[ct]=s; cq[ct]=q2;
    }
    #pragma unroll
    for (int jj=0;jj<2;jj++){
      int ct = quad*2 + jj, col = ct*16 + ml;
      hmax[(size_t)mrow*128 + col] = cm[ct];
      hmin[(size_t)mrow*128 + col] = cn[ct];
      atomicAdd(&ssum[col], cs[ct]);
      atomicAdd(&ssq[col],  cq[ct]);
    }
  }
  __syncthreads();
  int cp = (blockIdx.x & 31)*256;
  if (tid < 128){ atomicAdd(&S2[cp+tid], ssum[tid]); atomicAdd(&S2[cp+128+tid], ssq[tid]); }
}

// ---------- K8: bn2+relu on pooled extrema (P2 computed per-block from S2) ----------
__global__ __launch_bounds__(256) void k_pool(const float* __restrict__ hmax, const float* __restrict__ hmin,
                                              const float* __restrict__ g2v, const float* __restrict__ b2v,
                                              const float* __restrict__ S2, float* __restrict__ out1){
  __shared__ float ot[128*65];
  __shared__ float scs[128], shs[128];
  int tid = threadIdx.x, blk = blockIdx.x;
  int b = blk >> 4, m0 = (blk & 15) * 64;
  if (tid < 128){
    float s=0.f, q=0.f;
    for (int c=0;c<32;c++){ s += S2[c*256+tid]; q += S2[c*256+128+tid]; }
    float inv = 1.0f / (float)RTOT;
    float mean = s * inv;
    float var  = q * inv - mean*mean;
    float rs = 1.0f / sqrtf(var + 1e-5f);
    float scv = g2v[tid] * rs;
    scs[tid] = scv;
    shs[tid] = b2v[tid] - mean*scv;
  }
  __syncthreads();
  int ml = tid >> 2, oq = tid & 3, o0 = oq*32;
  int gm = b*MM + m0 + ml;
  const float4* xr = (const float4*)(hmax + (size_t)gm*128 + o0);
  const float4* nr = (const float4*)(hmin + (size_t)gm*128 + o0);
  #pragma unroll
  for (int j2=0;j2<8;j2++){
    float4 hx = xr[j2], hn = nr[j2];
    float hv[4] = {hx.x, hx.y, hx.z, hx.w};
    float nv[4] = {hn.x, hn.y, hn.z, hn.w};
    #pragma unroll
    for (int e=0;e<4;e++){
      int c = o0 + j2*4 + e;
      float sc = scs[c], sh = shs[c];
      float h = (sc >= 0.f) ? hv[e] : nv[e];
      ot[c*65 + ml] = fmaxf(fmaf(h, sc, sh), 0.f);
    }
  }
  __syncthreads();
  int o = tid >> 1, mh = tid & 1;
  float* dst = out1 + ((size_t)(b*COUT + o))*MM + m0 + mh*32;
  #pragma unroll
  for (int j2=0;j2<8;j2++){
    float4 v;
    v.x=ot[o*65+mh*32+j2*4+0]; v.y=ot[o*65+mh*32+j2*4+1];
    v.z=ot[o*65+mh*32+j2*4+2]; v.w=ot[o*65+mh*32+j2*4+3];
    *(float4*)(dst + j2*4) = v;
  }
}

extern "C" void kernel_launch(void* const* d_in, const int* in_sizes, int n_in,
                              void* d_out, int out_size, void* d_ws, size_t ws_size,
                              hipStream_t stream) {
  (void)in_sizes; (void)n_in; (void)out_size; (void)ws_size;
  const float* p1 = (const float*)d_in[0];
  const float* x1 = (const float*)d_in[1];
  const float* w1 = (const float*)d_in[2];
  const float* g1 = (const float*)d_in[3];
  const float* b1 = (const float*)d_in[4];
  const float* w2 = (const float*)d_in[5];
  const float* g2 = (const float*)d_in[6];
  const float* b2 = (const float*)d_in[7];
  float* out = (float*)d_out;
  float* ws  = (float*)d_ws;

  // ws map (float indices)
  uint16_t* xtb = (uint16_t*)ws;                    // [B,N,64] bf16
  float4* p1n   = (float4*)(ws + 2097152);          // [B,N]
  float*  p2w   = ws + 2621440;                     // [B,M,4]
  float*  S1    = ws + 2686976;                     // 8192
  float*  S2    = ws + 2695168;                     // 8192
  uint16_t* h1  = (uint16_t*)(ws + 2703872);        // [R,128] bf16
  float*  hmax  = ws + 19481088;                    // [B*M,128]
  float*  hmin  = ws + 21578240;                    // [B*M,128]
  int*    prog  = (int*)(ws + 23675392);            // 16 batches x stride 16
  int*    prep_done = (int*)(ws + 23675392) + 256;
  float*  outp2 = out;                              // [B,M,3]
  float*  out1  = out + 49152;                      // [B,128,M]

  hipMemsetAsync(prog, 0, 2048, stream);            // prog + prep_done

  void* args[] = { (void*)&p1, (void*)&x1, (void*)&w1,
                   (void*)&outp2, (void*)&p2w,
                   (void*)&p1n, (void*)&xtb, (void*)&S1,
                   (void*)&h1, (void*)&S1, (void*)&prog, (void*)&prep_done };
  hipLaunchCooperativeKernel((void*)k_pre2, dim3(256), dim3(512), args, 0, stream);

  k_gemm2<<<1024, 256, 0, stream>>>((const __hip_bfloat16*)h1, w2, g1, b1, S1, S2, hmax, hmin);
  k_pool<<<256, 256, 0, stream>>>(hmax, hmin, g2, b2, S2, out1);
}

// Round 5
// 937.042 us; speedup vs baseline: 1.1301x; 1.1301x over previous
//
#include <hip/hip_runtime.h>
#include <hip/hip_bf16.h>
#include <hip/hip_cooperative_groups.h>
#include <cstdint>

namespace cg = cooperative_groups;

// Problem constants
#define BB 16
#define NN 4096
#define MM 1024
#define KNB 16
#define CIN 64
#define COUT 128
#define RTOT (BB*MM*KNB)   // 262144 rows
#define AP1 104            // gemm1 LDS row stride (96 used + 8 pad), bf16
#define AP2 136            // gemm2 LDS row stride (128 + 8 pad), bf16

typedef __attribute__((ext_vector_type(8))) short short8v;
typedef __attribute__((ext_vector_type(4))) float floatx4;
typedef __attribute__((ext_vector_type(2))) float f32x2;
typedef __attribute__((ext_vector_type(2))) unsigned int uint2v;

// ---------- helpers ----------
__device__ __forceinline__ float bflo(uint32_t u){ return __uint_as_float(u << 16); }
__device__ __forceinline__ float bfhi(uint32_t u){ return __uint_as_float(u & 0xffff0000u); }
__device__ __forceinline__ uint32_t f2bf_pk(float a, float b){
  uint32_t ua = __float_as_uint(a), ub = __float_as_uint(b);
  ua += 0x7fffu + ((ua >> 16) & 1u);   // RNE
  ub += 0x7fffu + ((ub >> 16) & 1u);
  return (ua >> 16) | (ub & 0xffff0000u);
}
__device__ __forceinline__ uint16_t f2bf1(float a){
  uint32_t u = __float_as_uint(a);
  u += 0x7fffu + ((u >> 16) & 1u);
  return (uint16_t)(u >> 16);
}
template<int CTRL>
__device__ __forceinline__ float dpp_f(float v){
  return __int_as_float(__builtin_amdgcn_update_dpp(__float_as_int(v), __float_as_int(v), CTRL, 0xf, 0xf, false));
}
// all-VALU cross-row max combine (gfx950 permlane swaps); fallback to DS pipe
__device__ __forceinline__ float plmax16(float v){
#if __has_builtin(__builtin_amdgcn_permlane16_swap)
  uint2v r = __builtin_amdgcn_permlane16_swap(__float_as_uint(v), __float_as_uint(v), false, false);
  return fmaxf(__uint_as_float(r[0]), __uint_as_float(r[1]));
#else
  return fmaxf(v, __int_as_float(__builtin_amdgcn_ds_swizzle(__float_as_int(v), 0x401F)));
#endif
}
__device__ __forceinline__ float plmax32(float v){
#if __has_builtin(__builtin_amdgcn_permlane32_swap)
  uint2v r = __builtin_amdgcn_permlane32_swap(__float_as_uint(v), __float_as_uint(v), false, false);
  return fmaxf(__uint_as_float(r[0]), __uint_as_float(r[1]));
#else
  return fmaxf(v, __shfl_xor(v, 32));
#endif
}

// ---------- LDS ----------
struct FpsS { float4 pcv[NN]; float4 sel[MM]; unsigned long long candk[2][4]; }; // 81984 B
struct TrS  { float t[64][65]; };                                         // 16640 B
struct ConsS{ uint16_t Bh1[128*AP1]; uint16_t AhD[128*AP2];
              int winq[8*16]; float ssum[128]; float ssq[128]; };         // 62976 B
union PreU  { FpsS fps; TrS tr; ConsS cons; };

// ================= K1: FPS producer (blocks 0-15) || prework + pipelined kNN+GEMM1
//                       consumers (blocks 16-255) =================
// Producer v3 (MEASURED BEST, 719us — reverted byte-exact): 4 FPS waves x 1024 pts
// (1 wave/SIMD), all-VALU wave reduce (DPP rows + permlane16/32 swaps), 4-entry
// packed-u64 cross-wave merge via per-iter barrier, float4 LDS point store,
// flush/publish on idle wave 4.
__global__ __launch_bounds__(512, 2) void k_pre2(
    const float* __restrict__ p1, const float* __restrict__ x1,
    const float* __restrict__ w1,
    float* __restrict__ outp2, float* __restrict__ p2w,
    float4* __restrict__ p1n, uint16_t* __restrict__ xtb, float* __restrict__ Sz,
    uint16_t* __restrict__ h1, float* __restrict__ S1,
    int* __restrict__ prog, int* __restrict__ prep_done)
{
  __shared__ PreU u;
  const int blk = blockIdx.x, tid = threadIdx.x;
  const int lane = tid & 63, wid = tid >> 6;

  if (blk < 16){
    // ---------------- FPS producer ----------------
    int b = blk;
    const float* pb = p1 + (size_t)b*NN*3;
    {
      float4 f[6];
      const float4* src = (const float4*)(pb + tid*24);
      #pragma unroll
      for (int j=0;j<6;j++) f[j] = src[j];
      const float* fa = (const float*)f;
      #pragma unroll
      for (int j=0;j<8;j++)
        u.fps.pcv[tid*8 + j] = make_float4(fa[3*j], fa[3*j+1], fa[3*j+2], 0.f);
    }
    __syncthreads();                                   // B0
    float4 c00 = u.fps.pcv[0];
    float cx = c00.x, cy = c00.y, cz = c00.z;
    if (tid==64) u.fps.sel[0] = make_float4(cx, cy, cz, 0.f);

    // per-lane state: 16 consecutive points (lane-major ascending = global idx order)
    f32x2 px2[8] = {}, py2[8] = {}, pz2[8] = {}, ds2[8] = {};
    const int g0 = tid*16;
    if (wid < 4){
      #pragma unroll
      for (int j=0;j<8;j++){
        float4 a = u.fps.pcv[g0 + 2*j];
        float4 bq = u.fps.pcv[g0 + 2*j + 1];
        px2[j][0]=a.x; px2[j][1]=bq.x;
        py2[j][0]=a.y; py2[j][1]=bq.y;
        pz2[j][0]=a.z; pz2[j][1]=bq.z;
        ds2[j][0]=1e10f; ds2[j][1]=1e10f;
      }
    }

    for (int i=1;i<MM;i++){
      if (wid < 4){
        {
          #pragma clang fp contract(off)
          f32x2 cx2; cx2[0]=cx; cx2[1]=cx;
          f32x2 cy2; cy2[0]=cy; cy2[1]=cy;
          f32x2 cz2; cz2[0]=cz; cz2[1]=cz;
          #pragma unroll
          for (int j=0;j<8;j++){
            f32x2 dx = px2[j] - cx2;
            f32x2 dy = py2[j] - cy2;
            f32x2 dz = pz2[j] - cz2;
            f32x2 d  = dx*dx + dy*dy + dz*dz;   // ((x^2+y^2)+z^2), RN, no fma
            ds2[j] = __builtin_elementwise_min(ds2[j], d);
          }
        }
        // lane-local max (pk tree)
        f32x2 t0 = __builtin_elementwise_max(ds2[0], ds2[1]);
        f32x2 t1 = __builtin_elementwise_max(ds2[2], ds2[3]);
        f32x2 t2 = __builtin_elementwise_max(ds2[4], ds2[5]);
        f32x2 t3 = __builtin_elementwise_max(ds2[6], ds2[7]);
        f32x2 u0 = __builtin_elementwise_max(t0, t1);
        f32x2 u1 = __builtin_elementwise_max(t2, t3);
        f32x2 vv = __builtin_elementwise_max(u0, u1);
        float lm = fmaxf(vv[0], vv[1]);
        // first local index attaining lm (descending overwrite -> smallest wins)
        int li = g0 + 15;
        #pragma unroll
        for (int j=14;j>=0;j--){
          float ev = ds2[j>>1][j & 1];
          li = (ev == lm) ? (g0 + j) : li;
        }
        // wave max, all-VALU: 4 DPP row steps + permlane16/32 swaps
        float wm = lm;
        wm = fmaxf(wm, dpp_f<0xB1>(wm));    // quad xor1
        wm = fmaxf(wm, dpp_f<0x4E>(wm));    // quad xor2
        wm = fmaxf(wm, dpp_f<0x124>(wm));   // row_ror:4
        wm = fmaxf(wm, dpp_f<0x128>(wm));   // row_ror:8
        wm = plmax16(wm);
        wm = plmax32(wm);
        // first lane holding the max -> its first local index
        unsigned long long bmask = __ballot(lm == wm);
        int fl = __ffsll(bmask) - 1;
        int wi = __builtin_amdgcn_readlane(li, fl);
        if (lane == 0)
          u.fps.candk[i&1][wid] = (((unsigned long long)(unsigned)__float_as_uint(wm)) << 32)
                                   | (unsigned)(0xFFFFu ^ (unsigned)wi);
      }
      __syncthreads();
      if (wid < 4){
        const unsigned long long* cd = u.fps.candk[i&1];
        unsigned long long cq0=cd[0], cq1=cd[1], cq2=cd[2], cq3=cd[3];
        unsigned long long a0 = cq0>cq1?cq0:cq1, a1 = cq2>cq3?cq2:cq3;
        unsigned long long mb = a0>a1?a0:a1;
        int midx = (int)(0xFFFFu ^ (unsigned)(mb & 0xFFFFull));
        float4 cv = u.fps.pcv[midx];
        cx = cv.x; cy = cv.y; cz = cv.z;
        if (tid==64) u.fps.sel[i] = make_float4(cx, cy, cz, 0.f);
      } else if (wid == 4 && (i & 63) == 0){
        // flush previous 64 selections (sel[e] for e<=i-1 visible: written pre-barrier_{e+1})
        int e = i - 64 + lane;
        float4 s = u.fps.sel[e];
        float n2 = __fadd_rn(__fadd_rn(__fmul_rn(s.x,s.x),__fmul_rn(s.y,s.y)),__fmul_rn(s.z,s.z));
        *(float4*)(p2w + ((size_t)b*MM + e)*4) = make_float4(s.x, s.y, s.z, n2);
        if (lane == 0)
          __hip_atomic_store(&prog[b*16], i, __ATOMIC_RELEASE, __HIP_MEMORY_SCOPE_AGENT);
      }
    }
    __syncthreads();                                   // B_final
    if (wid == 4){
      int e = 960 + lane;
      float4 s = u.fps.sel[e];
      float n2 = __fadd_rn(__fadd_rn(__fmul_rn(s.x,s.x),__fmul_rn(s.y,s.y)),__fmul_rn(s.z,s.z));
      *(float4*)(p2w + ((size_t)b*MM + e)*4) = make_float4(s.x, s.y, s.z, n2);
      if (lane == 0)
        __hip_atomic_store(&prog[b*16], MM, __ATOMIC_RELEASE, __HIP_MEMORY_SCOPE_AGENT);
    }
    for (int e = tid; e < MM; e += 512){
      float4 s = u.fps.sel[e];
      float* o = outp2 + ((size_t)b*MM + e)*3;
      o[0]=s.x; o[1]=s.y; o[2]=s.z;
    }
  } else {
    // ---------------- prework ----------------
    for (int i = (blk-16)*512 + tid; i < 16384; i += 240*512) Sz[i] = 0.f;
    for (int i = (blk-16)*512 + tid; i < BB*NN; i += 240*512){
      float x = p1[(size_t)i*3+0], y = p1[(size_t)i*3+1], z = p1[(size_t)i*3+2];
      float n = __fadd_rn(__fadd_rn(__fmul_rn(x,x),__fmul_rn(y,y)),__fmul_rn(z,z));
      p1n[i] = make_float4(x,y,z,n);
    }
    for (int tile = blk-16; tile < 1024; tile += 240){
      int b = tile >> 6, n0 = (tile & 63)*64;
      __syncthreads();
      int c = tid >> 3, q = tid & 7;
      const float* src = x1 + ((size_t)(b*64 + c))*NN + n0 + q*8;
      float4 f0 = *(const float4*)src, f1 = *(const float4*)(src+4);
      u.tr.t[c][q*8+0]=f0.x; u.tr.t[c][q*8+1]=f0.y; u.tr.t[c][q*8+2]=f0.z; u.tr.t[c][q*8+3]=f0.w;
      u.tr.t[c][q*8+4]=f1.x; u.tr.t[c][q*8+5]=f1.y; u.tr.t[c][q*8+6]=f1.z; u.tr.t[c][q*8+7]=f1.w;
      __syncthreads();
      int n = tid >> 3;
      uint32_t* dst = (uint32_t*)(xtb + ((size_t)(b*NN + n0 + n))*64 + q*8);
      #pragma unroll
      for (int j=0;j<4;j++)
        dst[j] = f2bf_pk(u.tr.t[q*8+2*j][n], u.tr.t[q*8+2*j+1][n]);
    }
    __threadfence();
    __syncthreads();
    if (tid == 0) atomicAdd(prep_done, 1);
    // stage w1 -> Bh1 (K-perm [x(64)|rel(3)|0]); zero block stats (TrS dead; union switch)
    for (int e = tid; e < 128*96; e += 512){
      int o = e / 96, k = e - o*96;
      float v = (k < 64) ? w1[o*67 + 3 + k] : ((k < 67) ? w1[o*67 + (k-64)] : 0.f);
      u.cons.Bh1[o*AP1 + k] = f2bf1(v);
    }
    if (tid < 128){ u.cons.ssum[tid]=0.f; u.cons.ssq[tid]=0.f; }
    __syncthreads();
    // wait for all 240 prework blocks (p1n/xtb from other blocks)
    {
      int pv = 0, sp = 0;
      if (lane == 0) pv = __hip_atomic_load(prep_done, __ATOMIC_ACQUIRE, __HIP_MEMORY_SCOPE_AGENT);
      pv = __shfl(pv, 0);
      while (pv < 240 && sp < (1<<16)){
        __builtin_amdgcn_s_sleep(64);
        if (lane == 0) pv = __hip_atomic_load(prep_done, __ATOMIC_ACQUIRE, __HIP_MEMORY_SCOPE_AGENT);
        pv = __shfl(pv, 0); sp++;
      }
    }
    // ---------------- pipelined kNN + fused GEMM1, one query per wave-step ----------------
    int ml = lane & 15, quad = lane >> 4, seg = lane >> 4;
    int gw = (blk-16)*8 + wid;                 // [0,1920)
    for (int qi = gw; qi < BB*MM; qi += 1920){
      int b = qi & 15, m = qi >> 4;
      int q2 = b*MM + m;
      // wait for centroid m (acquire; 1.7us-granularity sleep to cut line contention)
      {
        int pv = 0, sp = 0;
        if (lane == 0) pv = __hip_atomic_load(&prog[b*16], __ATOMIC_ACQUIRE, __HIP_MEMORY_SCOPE_AGENT);
        pv = __shfl(pv, 0);
        while (pv <= m && sp < (1<<16)){
          __builtin_amdgcn_s_sleep(64);
          if (lane == 0) pv = __hip_atomic_load(&prog[b*16], __ATOMIC_ACQUIRE, __HIP_MEMORY_SCOPE_AGENT);
          pv = __shfl(pv, 0); sp++;
        }
      }
      const float4 qv = *(const float4*)(p2w + (size_t)q2*4);
      const float4* pbn = p1n + (size_t)b*NN;
      float bd[16]; int bi[16];
      #pragma unroll
      for (int s=0;s<16;s++){ bd[s] = 1e30f; bi[s] = 0; }
      float wv = 1e30f; int wslot = 0;

      #define KPROC(T, PV) { \
        float dot = fmaf(qv.z, (PV).z, fmaf(qv.y, (PV).y, __fmul_rn(qv.x, (PV).x))); \
        float d2 = __fsub_rn(__fadd_rn(qv.w, (PV).w), __fmul_rn(2.0f, dot)); \
        if (d2 < wv){ \
          int c = (T)*64 + lane; \
          _Pragma("unroll") \
          for (int s=0;s<16;s++) if (s==wslot){ bd[s]=d2; bi[s]=c; } \
          wv = bd[0]; wslot = 0; \
          _Pragma("unroll") \
          for (int s=1;s<16;s++) if (bd[s] > wv){ wv = bd[s]; wslot = s; } \
        } }

      float4 cur = pbn[lane];
      for (int t=0;t<63;t++){
        float4 nx = pbn[(t+1)*64 + lane];
        KPROC(t, cur);
        cur = nx;
      }
      KPROC(63, cur);
      #undef KPROC

      float lv = bd[0]; int ls = 0;
      #pragma unroll
      for (int s=1;s<16;s++) if (bd[s] < lv){ lv = bd[s]; ls = s; }
      for (int r=0;r<16;r++){
        float rv = lv; int rl = lane;
        #pragma unroll
        for (int off=32; off>=1; off>>=1){
          float ov = __shfl_xor(rv, off); int ol = __shfl_xor(rl, off);
          if (ov < rv || (ov == rv && ol < rl)){ rv = ov; rl = ol; }
        }
        if (lane == rl){
          int idx = 0;
          #pragma unroll
          for (int s=0;s<16;s++) if (s==ls) idx = bi[s];
          u.cons.winq[wid*16 + r] = idx;
          #pragma unroll
          for (int s=0;s<16;s++) if (s==ls) bd[s] = 1e30f;
          lv = bd[0]; ls = 0;
          #pragma unroll
          for (int s=1;s<16;s++) if (bd[s] < lv){ lv = bd[s]; ls = s; }
        }
      }
      // ---- fused GEMM1 for this query's 16 rows (wave-private LDS rows) ----
      int n = u.cons.winq[wid*16 + ml];        // same-wave DS order: winq writes done
      {
        const uint4* s4 = (const uint4*)(xtb + ((size_t)(b*NN + n))*64 + seg*16);
        uint4* d4 = (uint4*)(u.cons.AhD + (wid*16 + ml)*AP2 + seg*16);
        d4[0] = s4[0]; d4[1] = s4[1];
        if (seg == 0){
          const float* pp = p1 + ((size_t)(b*NN + n))*3;
          float rx = __fsub_rn(pp[0], qv.x);
          float ry = __fsub_rn(pp[1], qv.y);
          float rz = __fsub_rn(pp[2], qv.z);
          uint4* dr = (uint4*)(u.cons.AhD + (wid*16 + ml)*AP2 + 64);
          dr[0] = make_uint4(f2bf_pk(rx, ry), f2bf_pk(rz, 0.f), 0u, 0u);
          dr[1] = make_uint4(0u,0u,0u,0u);
          dr[2] = make_uint4(0u,0u,0u,0u);
          dr[3] = make_uint4(0u,0u,0u,0u);
        }
      }
      short8v af[3];
      #pragma unroll
      for (int kc=0;kc<3;kc++)
        af[kc] = *(const short8v*)(u.cons.AhD + (wid*16 + ml)*AP2 + kc*32 + quad*8);
      floatx4 acc[8];
      #pragma unroll
      for (int ct=0;ct<8;ct++) acc[ct] = (floatx4){0.f,0.f,0.f,0.f};
      #pragma unroll
      for (int ct=0;ct<8;ct++){
        #pragma unroll
        for (int kc=0;kc<3;kc++){
          short8v bf = *(const short8v*)(u.cons.Bh1 + (ct*16+ml)*AP1 + kc*32 + quad*8);
          acc[ct] = __builtin_amdgcn_mfma_f32_16x16x32_bf16(af[kc], bf, acc[ct], 0, 0, 0);
        }
      }
      float csum[8], csq[8];
      #pragma unroll
      for (int ct=0;ct<8;ct++){
        float a0=acc[ct][0], a1=acc[ct][1], a2=acc[ct][2], a3=acc[ct][3];
        float s = (a0+a1)+(a2+a3);
        float qq2 = (a0*a0+a1*a1)+(a2*a2+a3*a3);
        s += __shfl_xor(s,16);  s += __shfl_xor(s,32);
        qq2 += __shfl_xor(qq2,16); qq2 += __shfl_xor(qq2,32);
        csum[ct]=s; csq[ct]=qq2;
        #pragma unroll
        for (int r=0;r<4;r++)
          u.cons.AhD[(wid*16 + quad*4 + r)*AP2 + ct*16 + ml] = f2bf1(acc[ct][r]);
      }
      #pragma unroll
      for (int jj=0;jj<2;jj++){
        int ct = quad*2 + jj, col = ct*16 + ml;
        atomicAdd(&u.cons.ssum[col], csum[ct]);
        atomicAdd(&u.cons.ssq[col],  csq[ct]);
      }
      // coalesced h1 write of own 16 rows (reads after same-wave D writes)
      {
        const uint4* s4 = (const uint4*)(u.cons.AhD + (wid*16 + ml)*AP2 + seg*32);
        uint4* dst = (uint4*)(h1 + ((size_t)q2*16 + ml)*128 + seg*32);
        dst[0]=s4[0]; dst[1]=s4[1]; dst[2]=s4[2]; dst[3]=s4[3];
      }
    }
    __syncthreads();
    int cp = (blk & 31)*256;
    if (tid < 128){ atomicAdd(&S1[cp+tid], u.cons.ssum[tid]); atomicAdd(&S1[cp+128+tid], u.cons.ssq[tid]); }
  }
}

// ---------- K6p: FUSED GEMM2 + k-pool + BN2 + out1 write ----------
// 256 blocks x 512 threads, 1 block/CU (cooperative launch guarantees residency).
// Each block: 16 tiles of 64 h1-rows (contiguous 256KB), per-m extrema kept in LDS
// (never round-trip HBM), S2 stats via 32-copy global atomics; device-wide arrival
// counter (all blocks resident -> spin is deadlock-free), then BN2+relu+transpose
// and out1 write. Arithmetic identical to the former k_gemm2 + k_pool.
union GU { struct { __hip_bfloat16 Ah[64*AP2]; __hip_bfloat16 Bh[128*AP2]; } g;  // 52224 B
           float ot[128*65]; };                                                  // 33280 B
__global__ __launch_bounds__(512) void k_gemm2p(const __hip_bfloat16* __restrict__ h1,
                                                const float* __restrict__ w2,
                                                const float* __restrict__ g1v, const float* __restrict__ b1v,
                                                const float* __restrict__ S1, float* __restrict__ S2,
                                                const float* __restrict__ g2v, const float* __restrict__ b2v,
                                                float* __restrict__ out1, int* __restrict__ done2){
  __shared__ GU su;                       // 52224
  __shared__ float ex[64][128];           // 32768
  __shared__ float en[64][128];           // 32768
  __shared__ float scb[128], shb[128], ssumb[128], ssqb[128], scs[128], shs[128]; // 3072
  int tid = threadIdx.x;
  // BN1 scale/shift from S1
  if (tid < 128){
    float s=0.f, q=0.f;
    for (int c=0;c<32;c++){ s += S1[c*256+tid]; q += S1[c*256+128+tid]; }
    float inv = 1.0f / (float)RTOT;
    float mean = s * inv;
    float var  = q * inv - mean*mean;
    float rs = 1.0f / sqrtf(var + 1e-5f);
    float scv = g1v[tid] * rs;
    scb[tid] = scv;
    shb[tid] = b1v[tid] - mean*scv;
    ssumb[tid] = 0.f; ssqb[tid] = 0.f;
  }
  // stage w2 -> Bh (512 threads: 128 rows x 4 col-groups of 32)
  {
    int o = tid >> 2, q4 = tid & 3;
    const float4* wr = (const float4*)(w2 + (size_t)o*128 + q4*32);
    uint32_t* bd = (uint32_t*)(su.g.Bh + o*AP2 + q4*32);
    #pragma unroll
    for (int q=0;q<8;q++){
      float4 v = wr[q];
      bd[2*q]   = f2bf_pk(v.x, v.y);
      bd[2*q+1] = f2bf_pk(v.z, v.w);
    }
  }
  __syncthreads();
  int lane = tid & 63, wid = tid >> 6;      // 8 waves
  int wm0 = (wid >> 1) * 16;                // 4 row-groups of 16 (one m each)
  int cth = (wid & 1) * 4;                  // ct half: 0-3 or 4-7
  int ml = lane & 15, quad = lane >> 4;
  for (int j = 0; j < 16; j++){
    int tile = blockIdx.x*16 + j;
    int r0 = tile * 64;
    if (j) __syncthreads();
    // load + BN1 + relu + repack: 512 threads, each 1 row x 16 cols (2 uint4)
    {
      int row = tid >> 3, seg = tid & 7;
      const uint4* hp4 = (const uint4*)(h1 + ((size_t)(r0+row))*128 + seg*16);
      #pragma unroll
      for (int q=0;q<2;q++){
        uint4 uu = hp4[q];
        int cg = seg*16 + q*8;
        uint32_t wv[4] = {uu.x,uu.y,uu.z,uu.w};
        uint32_t ov[4];
        #pragma unroll
        for (int t=0;t<4;t++){
          int c = cg + t*2;
          float a0 = fmaxf(fmaf(bflo(wv[t]), scb[c],   shb[c]),   0.f);
          float a1 = fmaxf(fmaf(bfhi(wv[t]), scb[c+1], shb[c+1]), 0.f);
          ov[t] = f2bf_pk(a0, a1);
        }
        *(uint4*)(su.g.Ah + row*AP2 + cg) = make_uint4(ov[0],ov[1],ov[2],ov[3]);
      }
    }
    __syncthreads();
    short8v af[4];
    #pragma unroll
    for (int kc=0;kc<4;kc++)
      af[kc] = *(const short8v*)(su.g.Ah + (wm0+ml)*AP2 + kc*32 + quad*8);
    floatx4 acc[4];
    #pragma unroll
    for (int c4=0;c4<4;c4++) acc[c4] = (floatx4){0.f,0.f,0.f,0.f};
    #pragma unroll
    for (int c4=0;c4<4;c4++){
      #pragma unroll
      for (int kc=0;kc<4;kc++){
        short8v bf = *(const short8v*)(su.g.Bh + ((cth+c4)*16+ml)*AP2 + kc*32 + quad*8);
        acc[c4] = __builtin_amdgcn_mfma_f32_16x16x32_bf16(af[kc], bf, acc[c4], 0, 0, 0);
      }
    }
    int mloc = j*4 + (wid >> 1);            // local m in [0,64)
    float cm[4], cn[4], cs[4], cq[4];
    #pragma unroll
    for (int c4=0;c4<4;c4++){
      float a0=acc[c4][0], a1=acc[c4][1], a2=acc[c4][2], a3=acc[c4][3];
      float mx = fmaxf(fmaxf(a0,a1), fmaxf(a2,a3));
      float mn = fminf(fminf(a0,a1), fminf(a2,a3));
      float s  = (a0+a1)+(a2+a3);
      float q2 = (a0*a0+a1*a1)+(a2*a2+a3*a3);
      mx = fmaxf(mx, __shfl_xor(mx,16)); mx = fmaxf(mx, __shfl_xor(mx,32));
      mn = fminf(mn, __shfl_xor(mn,16)); mn = fminf(mn, __shfl_xor(mn,32));
      s += __shfl_xor(s,16);  s += __shfl_xor(s,32);
      q2 += __shfl_xor(q2,16); q2 += __shfl_xor(q2,32);
      cm[c4]=mx; cn[c4]=mn; cs[c4]=s; cq[c4]=q2;
    }
    // lane writes its quad's ct: col = (cth+quad)*16+ml
    {
      float vmx = (quad==0)?cm[0]:((quad==1)?cm[1]:((quad==2)?cm[2]:cm[3]));
      float vmn = (quad==0)?cn[0]:((quad==1)?cn[1]:((quad==2)?cn[2]:cn[3]));
      float vs  = (quad==0)?cs[0]:((quad==1)?cs[1]:((quad==2)?cs[2]:cs[3]));
      float vq  = (quad==0)?cq[0]:((quad==1)?cq[1]:((quad==2)?cq[2]:cq[3]));
      int col = (cth + quad)*16 + ml;
      ex[mloc][col] = vmx;
      en[mloc][col] = vmn;
      atomicAdd(&ssumb[col], vs);
      atomicAdd(&ssqb[col],  vq);
    }
  }
  __syncthreads();
  // flush block stats to S2 (32 copies), then device-wide arrival
  {
    int cp = (blockIdx.x & 31)*256;
    if (tid < 128){ atomicAdd(&S2[cp+tid], ssumb[tid]); atomicAdd(&S2[cp+128+tid], ssqb[tid]); }
  }
  __threadfence();
  __syncthreads();
  if (tid == 0) __hip_atomic_fetch_add(done2, 1, __ATOMIC_ACQ_REL, __HIP_MEMORY_SCOPE_AGENT);
  // spin until all 256 blocks arrived (cooperative launch -> all resident)
  {
    int dv = 0, sp = 0;
    if (tid == 0){
      do {
        dv = __hip_atomic_load(done2, __ATOMIC_ACQUIRE, __HIP_MEMORY_SCOPE_AGENT);
        if (dv >= 256) break;
        __builtin_amdgcn_s_sleep(32);
      } while (++sp < (1<<22));
    }
    __syncthreads();
  }
  // BN2 scale/shift from S2
  if (tid < 128){
    float s=0.f, q=0.f;
    for (int c=0;c<32;c++){ s += S2[c*256+tid]; q += S2[c*256+128+tid]; }
    float inv = 1.0f / (float)RTOT;
    float mean = s * inv;
    float var  = q * inv - mean*mean;
    float rs = 1.0f / sqrtf(var + 1e-5f);
    float scv = g2v[tid] * rs;
    scs[tid] = scv;
    shs[tid] = b2v[tid] - mean*scv;
  }
  __syncthreads();
  // BN2 + relu on extrema (select max/min by sign), transpose into ot (GU reuse: Ah/Bh dead)
  {
    int m2 = tid >> 3, oq = tid & 7, o0 = oq*16;
    #pragma unroll
    for (int e=0;e<16;e++){
      int c = o0 + e;
      float sc = scs[c], sh = shs[c];
      float h = (sc >= 0.f) ? ex[m2][c] : en[m2][c];
      su.ot[c*65 + m2] = fmaxf(fmaf(h, sc, sh), 0.f);
    }
  }
  __syncthreads();
  // write out1: block covers batch b, m-range [m0, m0+64)
  {
    int b = blockIdx.x >> 4, m0 = (blockIdx.x & 15)*64;
    int o = tid >> 2, qr = tid & 3;
    float* dst = out1 + ((size_t)(b*COUT + o))*MM + m0 + qr*16;
    #pragma unroll
    for (int e=0;e<4;e++){
      float4 v;
      v.x = su.ot[o*65 + qr*16 + e*4 + 0];
      v.y = su.ot[o*65 + qr*16 + e*4 + 1];
      v.z = su.ot[o*65 + qr*16 + e*4 + 2];
      v.w = su.ot[o*65 + qr*16 + e*4 + 3];
      *(float4*)(dst + e*4) = v;
    }
  }
}

extern "C" void kernel_launch(void* const* d_in, const int* in_sizes, int n_in,
                              void* d_out, int out_size, void* d_ws, size_t ws_size,
                              hipStream_t stream) {
  (void)in_sizes; (void)n_in; (void)out_size; (void)ws_size;
  const float* p1 = (const float*)d_in[0];
  const float* x1 = (const float*)d_in[1];
  const float* w1 = (const float*)d_in[2];
  const float* g1 = (const float*)d_in[3];
  const float* b1 = (const float*)d_in[4];
  const float* w2 = (const float*)d_in[5];
  const float* g2 = (const float*)d_in[6];
  const float* b2 = (const float*)d_in[7];
  float* out = (float*)d_out;
  float* ws  = (float*)d_ws;

  // ws map (float indices)
  uint16_t* xtb = (uint16_t*)ws;                    // [B,N,64] bf16
  float4* p1n   = (float4*)(ws + 2097152);          // [B,N]
  float*  p2w   = ws + 2621440;                     // [B,M,4]
  float*  S1    = ws + 2686976;                     // 8192
  float*  S2    = ws + 2695168;                     // 8192
  uint16_t* h1  = (uint16_t*)(ws + 2703872);        // [R,128] bf16
  int*    prog  = (int*)(ws + 23675392);            // 16 batches x stride 16
  int*    prep_done = (int*)(ws + 23675392) + 256;
  int*    done2 = (int*)(ws + 23675392) + 257;
  float*  outp2 = out;                              // [B,M,3]
  float*  out1  = out + 49152;                      // [B,128,M]

  hipMemsetAsync(prog, 0, 2048, stream);            // prog + prep_done + done2

  void* args[] = { (void*)&p1, (void*)&x1, (void*)&w1,
                   (void*)&outp2, (void*)&p2w,
                   (void*)&p1n, (void*)&xtb, (void*)&S1,
                   (void*)&h1, (void*)&S1, (void*)&prog, (void*)&prep_done };
  hipLaunchCooperativeKernel((void*)k_pre2, dim3(256), dim3(512), args, 0, stream);

  const __hip_bfloat16* h1b = (const __hip_bfloat16*)h1;
  void* args2[] = { (void*)&h1b, (void*)&w2, (void*)&g1, (void*)&b1,
                    (void*)&S1, (void*)&S2, (void*)&g2, (void*)&b2,
                    (void*)&out1, (void*)&done2 };
  hipLaunchCooperativeKernel((void*)k_gemm2p, dim3(256), dim3(512), args2, 0, stream);
}

// Round 6
// 831.527 us; speedup vs baseline: 1.2735x; 1.1269x over previous
//
#include <hip/hip_runtime.h>
#include <hip/hip_bf16.h>
#include <hip/hip_cooperative_groups.h>
#include <cstdint>

namespace cg = cooperative_groups;

// Problem constants
#define BB 16
#define NN 4096
#define MM 1024
#define KNB 16
#define CIN 64
#define COUT 128
#define RTOT (BB*MM*KNB)   // 262144 rows
#define AP1 104            // gemm1 LDS row stride (96 used + 8 pad), bf16
#define AP2 136            // gemm2 LDS row stride (128 + 8 pad), bf16

typedef __attribute__((ext_vector_type(8))) short short8v;
typedef __attribute__((ext_vector_type(4))) float floatx4;
typedef __attribute__((ext_vector_type(2))) float f32x2;
typedef __attribute__((ext_vector_type(2))) unsigned int uint2v;

// ---------- helpers ----------
__device__ __forceinline__ float bflo(uint32_t u){ return __uint_as_float(u << 16); }
__device__ __forceinline__ float bfhi(uint32_t u){ return __uint_as_float(u & 0xffff0000u); }
__device__ __forceinline__ uint32_t f2bf_pk(float a, float b){
  uint32_t ua = __float_as_uint(a), ub = __float_as_uint(b);
  ua += 0x7fffu + ((ua >> 16) & 1u);   // RNE
  ub += 0x7fffu + ((ub >> 16) & 1u);
  return (ua >> 16) | (ub & 0xffff0000u);
}
__device__ __forceinline__ uint16_t f2bf1(float a){
  uint32_t u = __float_as_uint(a);
  u += 0x7fffu + ((u >> 16) & 1u);
  return (uint16_t)(u >> 16);
}
template<int CTRL>
__device__ __forceinline__ float dpp_f(float v){
  return __int_as_float(__builtin_amdgcn_update_dpp(__float_as_int(v), __float_as_int(v), CTRL, 0xf, 0xf, false));
}
// all-VALU cross-row max combine (gfx950 permlane swaps); fallback to DS pipe
__device__ __forceinline__ float plmax16(float v){
#if __has_builtin(__builtin_amdgcn_permlane16_swap)
  uint2v r = __builtin_amdgcn_permlane16_swap(__float_as_uint(v), __float_as_uint(v), false, false);
  return fmaxf(__uint_as_float(r[0]), __uint_as_float(r[1]));
#else
  return fmaxf(v, __int_as_float(__builtin_amdgcn_ds_swizzle(__float_as_int(v), 0x401F)));
#endif
}
__device__ __forceinline__ float plmax32(float v){
#if __has_builtin(__builtin_amdgcn_permlane32_swap)
  uint2v r = __builtin_amdgcn_permlane32_swap(__float_as_uint(v), __float_as_uint(v), false, false);
  return fmaxf(__uint_as_float(r[0]), __uint_as_float(r[1]));
#else
  return fmaxf(v, __shfl_xor(v, 32));
#endif
}

// ---------- LDS ----------
struct FpsS { float4 pcv[NN]; float4 sel[MM]; unsigned long long candk[2][4]; }; // 81984 B
struct TrS  { float t[64][65]; };                                         // 16640 B
struct ConsS{ uint16_t Bh1[128*AP1]; uint16_t AhD[128*AP2];
              int winq[8*16]; float ssum[128]; float ssq[128]; };         // 62976 B
union PreU  { FpsS fps; TrS tr; ConsS cons; };

// ================= K1: FPS producer (blocks 0-15) || prework + pipelined kNN+GEMM1
//                       consumers (blocks 16-255) =================
// Producer v3 (MEASURED BEST, ~715us): 4 FPS waves x 1024 pts (1 wave/SIMD),
// all-VALU wave reduce (DPP rows + permlane16/32 swaps), 4-entry packed-u64
// cross-wave merge via per-iter barrier, float4 LDS point store, flush/publish
// on idle wave 4. LDS 82KB -> exactly 1 block/CU -> regular launch of 256 blocks
// on 256 CUs gives de-facto co-residency (coop launch semantics not required;
// R5 measured +77us overhead per extra cooperative launch).
__global__ __launch_bounds__(512, 2) void k_pre2(
    const float* __restrict__ p1, const float* __restrict__ x1,
    const float* __restrict__ w1,
    float* __restrict__ outp2, float* __restrict__ p2w,
    float4* __restrict__ p1n, uint16_t* __restrict__ xtb, float* __restrict__ Sz,
    uint16_t* __restrict__ h1, float* __restrict__ S1,
    int* __restrict__ prog, int* __restrict__ prep_done)
{
  __shared__ PreU u;
  const int blk = blockIdx.x, tid = threadIdx.x;
  const int lane = tid & 63, wid = tid >> 6;

  if (blk < 16){
    // ---------------- FPS producer ----------------
    int b = blk;
    const float* pb = p1 + (size_t)b*NN*3;
    {
      float4 f[6];
      const float4* src = (const float4*)(pb + tid*24);
      #pragma unroll
      for (int j=0;j<6;j++) f[j] = src[j];
      const float* fa = (const float*)f;
      #pragma unroll
      for (int j=0;j<8;j++)
        u.fps.pcv[tid*8 + j] = make_float4(fa[3*j], fa[3*j+1], fa[3*j+2], 0.f);
    }
    __syncthreads();                                   // B0
    float4 c00 = u.fps.pcv[0];
    float cx = c00.x, cy = c00.y, cz = c00.z;
    if (tid==64) u.fps.sel[0] = make_float4(cx, cy, cz, 0.f);

    // per-lane state: 16 consecutive points (lane-major ascending = global idx order)
    f32x2 px2[8] = {}, py2[8] = {}, pz2[8] = {}, ds2[8] = {};
    const int g0 = tid*16;
    if (wid < 4){
      #pragma unroll
      for (int j=0;j<8;j++){
        float4 a = u.fps.pcv[g0 + 2*j];
        float4 bq = u.fps.pcv[g0 + 2*j + 1];
        px2[j][0]=a.x; px2[j][1]=bq.x;
        py2[j][0]=a.y; py2[j][1]=bq.y;
        pz2[j][0]=a.z; pz2[j][1]=bq.z;
        ds2[j][0]=1e10f; ds2[j][1]=1e10f;
      }
    }

    for (int i=1;i<MM;i++){
      if (wid < 4){
        {
          #pragma clang fp contract(off)
          f32x2 cx2; cx2[0]=cx; cx2[1]=cx;
          f32x2 cy2; cy2[0]=cy; cy2[1]=cy;
          f32x2 cz2; cz2[0]=cz; cz2[1]=cz;
          #pragma unroll
          for (int j=0;j<8;j++){
            f32x2 dx = px2[j] - cx2;
            f32x2 dy = py2[j] - cy2;
            f32x2 dz = pz2[j] - cz2;
            f32x2 d  = dx*dx + dy*dy + dz*dz;   // ((x^2+y^2)+z^2), RN, no fma
            ds2[j] = __builtin_elementwise_min(ds2[j], d);
          }
        }
        // lane-local max (pk tree)
        f32x2 t0 = __builtin_elementwise_max(ds2[0], ds2[1]);
        f32x2 t1 = __builtin_elementwise_max(ds2[2], ds2[3]);
        f32x2 t2 = __builtin_elementwise_max(ds2[4], ds2[5]);
        f32x2 t3 = __builtin_elementwise_max(ds2[6], ds2[7]);
        f32x2 u0 = __builtin_elementwise_max(t0, t1);
        f32x2 u1 = __builtin_elementwise_max(t2, t3);
        f32x2 vv = __builtin_elementwise_max(u0, u1);
        float lm = fmaxf(vv[0], vv[1]);
        // first local index attaining lm (descending overwrite -> smallest wins)
        int li = g0 + 15;
        #pragma unroll
        for (int j=14;j>=0;j--){
          float ev = ds2[j>>1][j & 1];
          li = (ev == lm) ? (g0 + j) : li;
        }
        // wave max, all-VALU: 4 DPP row steps + permlane16/32 swaps
        float wm = lm;
        wm = fmaxf(wm, dpp_f<0xB1>(wm));    // quad xor1
        wm = fmaxf(wm, dpp_f<0x4E>(wm));    // quad xor2
        wm = fmaxf(wm, dpp_f<0x124>(wm));   // row_ror:4
        wm = fmaxf(wm, dpp_f<0x128>(wm));   // row_ror:8
        wm = plmax16(wm);
        wm = plmax32(wm);
        // first lane holding the max -> its first local index
        unsigned long long bmask = __ballot(lm == wm);
        int fl = __ffsll(bmask) - 1;
        int wi = __builtin_amdgcn_readlane(li, fl);
        if (lane == 0)
          u.fps.candk[i&1][wid] = (((unsigned long long)(unsigned)__float_as_uint(wm)) << 32)
                                   | (unsigned)(0xFFFFu ^ (unsigned)wi);
      }
      __syncthreads();
      if (wid < 4){
        const unsigned long long* cd = u.fps.candk[i&1];
        unsigned long long cq0=cd[0], cq1=cd[1], cq2=cd[2], cq3=cd[3];
        unsigned long long a0 = cq0>cq1?cq0:cq1, a1 = cq2>cq3?cq2:cq3;
        unsigned long long mb = a0>a1?a0:a1;
        int midx = (int)(0xFFFFu ^ (unsigned)(mb & 0xFFFFull));
        float4 cv = u.fps.pcv[midx];
        cx = cv.x; cy = cv.y; cz = cv.z;
        if (tid==64) u.fps.sel[i] = make_float4(cx, cy, cz, 0.f);
      } else if (wid == 4 && (i & 63) == 0){
        // flush previous 64 selections (sel[e] for e<=i-1 visible: written pre-barrier_{e+1})
        int e = i - 64 + lane;
        float4 s = u.fps.sel[e];
        float n2 = __fadd_rn(__fadd_rn(__fmul_rn(s.x,s.x),__fmul_rn(s.y,s.y)),__fmul_rn(s.z,s.z));
        *(float4*)(p2w + ((size_t)b*MM + e)*4) = make_float4(s.x, s.y, s.z, n2);
        if (lane == 0)
          __hip_atomic_store(&prog[b*16], i, __ATOMIC_RELEASE, __HIP_MEMORY_SCOPE_AGENT);
      }
    }
    __syncthreads();                                   // B_final
    if (wid == 4){
      int e = 960 + lane;
      float4 s = u.fps.sel[e];
      float n2 = __fadd_rn(__fadd_rn(__fmul_rn(s.x,s.x),__fmul_rn(s.y,s.y)),__fmul_rn(s.z,s.z));
      *(float4*)(p2w + ((size_t)b*MM + e)*4) = make_float4(s.x, s.y, s.z, n2);
      if (lane == 0)
        __hip_atomic_store(&prog[b*16], MM, __ATOMIC_RELEASE, __HIP_MEMORY_SCOPE_AGENT);
    }
    for (int e = tid; e < MM; e += 512){
      float4 s = u.fps.sel[e];
      float* o = outp2 + ((size_t)b*MM + e)*3;
      o[0]=s.x; o[1]=s.y; o[2]=s.z;
    }
  } else {
    // ---------------- prework ----------------
    for (int i = (blk-16)*512 + tid; i < 16384; i += 240*512) Sz[i] = 0.f;
    for (int i = (blk-16)*512 + tid; i < BB*NN; i += 240*512){
      float x = p1[(size_t)i*3+0], y = p1[(size_t)i*3+1], z = p1[(size_t)i*3+2];
      float n = __fadd_rn(__fadd_rn(__fmul_rn(x,x),__fmul_rn(y,y)),__fmul_rn(z,z));
      p1n[i] = make_float4(x,y,z,n);
    }
    for (int tile = blk-16; tile < 1024; tile += 240){
      int b = tile >> 6, n0 = (tile & 63)*64;
      __syncthreads();
      int c = tid >> 3, q = tid & 7;
      const float* src = x1 + ((size_t)(b*64 + c))*NN + n0 + q*8;
      float4 f0 = *(const float4*)src, f1 = *(const float4*)(src+4);
      u.tr.t[c][q*8+0]=f0.x; u.tr.t[c][q*8+1]=f0.y; u.tr.t[c][q*8+2]=f0.z; u.tr.t[c][q*8+3]=f0.w;
      u.tr.t[c][q*8+4]=f1.x; u.tr.t[c][q*8+5]=f1.y; u.tr.t[c][q*8+6]=f1.z; u.tr.t[c][q*8+7]=f1.w;
      __syncthreads();
      int n = tid >> 3;
      uint32_t* dst = (uint32_t*)(xtb + ((size_t)(b*NN + n0 + n))*64 + q*8);
      #pragma unroll
      for (int j=0;j<4;j++)
        dst[j] = f2bf_pk(u.tr.t[q*8+2*j][n], u.tr.t[q*8+2*j+1][n]);
    }
    __threadfence();
    __syncthreads();
    if (tid == 0) atomicAdd(prep_done, 1);
    // stage w1 -> Bh1 (K-perm [x(64)|rel(3)|0]); zero block stats (TrS dead; union switch)
    for (int e = tid; e < 128*96; e += 512){
      int o = e / 96, k = e - o*96;
      float v = (k < 64) ? w1[o*67 + 3 + k] : ((k < 67) ? w1[o*67 + (k-64)] : 0.f);
      u.cons.Bh1[o*AP1 + k] = f2bf1(v);
    }
    if (tid < 128){ u.cons.ssum[tid]=0.f; u.cons.ssq[tid]=0.f; }
    __syncthreads();
    // wait for all 240 prework blocks (p1n/xtb from other blocks)
    {
      int pv = 0, sp = 0;
      if (lane == 0) pv = __hip_atomic_load(prep_done, __ATOMIC_ACQUIRE, __HIP_MEMORY_SCOPE_AGENT);
      pv = __shfl(pv, 0);
      while (pv < 240 && sp < (1<<16)){
        __builtin_amdgcn_s_sleep(64);
        if (lane == 0) pv = __hip_atomic_load(prep_done, __ATOMIC_ACQUIRE, __HIP_MEMORY_SCOPE_AGENT);
        pv = __shfl(pv, 0); sp++;
      }
    }
    // ---------------- pipelined kNN + fused GEMM1, one query per wave-step ----------------
    int ml = lane & 15, quad = lane >> 4, seg = lane >> 4;
    int gw = (blk-16)*8 + wid;                 // [0,1920)
    for (int qi = gw; qi < BB*MM; qi += 1920){
      int b = qi & 15, m = qi >> 4;
      int q2 = b*MM + m;
      // wait for centroid m (acquire; 1.7us-granularity sleep to cut line contention)
      {
        int pv = 0, sp = 0;
        if (lane == 0) pv = __hip_atomic_load(&prog[b*16], __ATOMIC_ACQUIRE, __HIP_MEMORY_SCOPE_AGENT);
        pv = __shfl(pv, 0);
        while (pv <= m && sp < (1<<16)){
          __builtin_amdgcn_s_sleep(64);
          if (lane == 0) pv = __hip_atomic_load(&prog[b*16], __ATOMIC_ACQUIRE, __HIP_MEMORY_SCOPE_AGENT);
          pv = __shfl(pv, 0); sp++;
        }
      }
      const float4 qv = *(const float4*)(p2w + (size_t)q2*4);
      const float4* pbn = p1n + (size_t)b*NN;
      float bd[16]; int bi[16];
      #pragma unroll
      for (int s=0;s<16;s++){ bd[s] = 1e30f; bi[s] = 0; }
      float wv = 1e30f; int wslot = 0;

      #define KPROC(T, PV) { \
        float dot = fmaf(qv.z, (PV).z, fmaf(qv.y, (PV).y, __fmul_rn(qv.x, (PV).x))); \
        float d2 = __fsub_rn(__fadd_rn(qv.w, (PV).w), __fmul_rn(2.0f, dot)); \
        if (d2 < wv){ \
          int c = (T)*64 + lane; \
          _Pragma("unroll") \
          for (int s=0;s<16;s++) if (s==wslot){ bd[s]=d2; bi[s]=c; } \
          wv = bd[0]; wslot = 0; \
          _Pragma("unroll") \
          for (int s=1;s<16;s++) if (bd[s] > wv){ wv = bd[s]; wslot = s; } \
        } }

      float4 cur = pbn[lane];
      for (int t=0;t<63;t++){
        float4 nx = pbn[(t+1)*64 + lane];
        KPROC(t, cur);
        cur = nx;
      }
      KPROC(63, cur);
      #undef KPROC

      float lv = bd[0]; int ls = 0;
      #pragma unroll
      for (int s=1;s<16;s++) if (bd[s] < lv){ lv = bd[s]; ls = s; }
      for (int r=0;r<16;r++){
        float rv = lv; int rl = lane;
        #pragma unroll
        for (int off=32; off>=1; off>>=1){
          float ov = __shfl_xor(rv, off); int ol = __shfl_xor(rl, off);
          if (ov < rv || (ov == rv && ol < rl)){ rv = ov; rl = ol; }
        }
        if (lane == rl){
          int idx = 0;
          #pragma unroll
          for (int s=0;s<16;s++) if (s==ls) idx = bi[s];
          u.cons.winq[wid*16 + r] = idx;
          #pragma unroll
          for (int s=0;s<16;s++) if (s==ls) bd[s] = 1e30f;
          lv = bd[0]; ls = 0;
          #pragma unroll
          for (int s=1;s<16;s++) if (bd[s] < lv){ lv = bd[s]; ls = s; }
        }
      }
      // ---- fused GEMM1 for this query's 16 rows (wave-private LDS rows) ----
      int n = u.cons.winq[wid*16 + ml];        // same-wave DS order: winq writes done
      {
        const uint4* s4 = (const uint4*)(xtb + ((size_t)(b*NN + n))*64 + seg*16);
        uint4* d4 = (uint4*)(u.cons.AhD + (wid*16 + ml)*AP2 + seg*16);
        d4[0] = s4[0]; d4[1] = s4[1];
        if (seg == 0){
          const float* pp = p1 + ((size_t)(b*NN + n))*3;
          float rx = __fsub_rn(pp[0], qv.x);
          float ry = __fsub_rn(pp[1], qv.y);
          float rz = __fsub_rn(pp[2], qv.z);
          uint4* dr = (uint4*)(u.cons.AhD + (wid*16 + ml)*AP2 + 64);
          dr[0] = make_uint4(f2bf_pk(rx, ry), f2bf_pk(rz, 0.f), 0u, 0u);
          dr[1] = make_uint4(0u,0u,0u,0u);
          dr[2] = make_uint4(0u,0u,0u,0u);
          dr[3] = make_uint4(0u,0u,0u,0u);
        }
      }
      short8v af[3];
      #pragma unroll
      for (int kc=0;kc<3;kc++)
        af[kc] = *(const short8v*)(u.cons.AhD + (wid*16 + ml)*AP2 + kc*32 + quad*8);
      floatx4 acc[8];
      #pragma unroll
      for (int ct=0;ct<8;ct++) acc[ct] = (floatx4){0.f,0.f,0.f,0.f};
      #pragma unroll
      for (int ct=0;ct<8;ct++){
        #pragma unroll
        for (int kc=0;kc<3;kc++){
          short8v bf = *(const short8v*)(u.cons.Bh1 + (ct*16+ml)*AP1 + kc*32 + quad*8);
          acc[ct] = __builtin_amdgcn_mfma_f32_16x16x32_bf16(af[kc], bf, acc[ct], 0, 0, 0);
        }
      }
      float csum[8], csq[8];
      #pragma unroll
      for (int ct=0;ct<8;ct++){
        float a0=acc[ct][0], a1=acc[ct][1], a2=acc[ct][2], a3=acc[ct][3];
        float s = (a0+a1)+(a2+a3);
        float qq2 = (a0*a0+a1*a1)+(a2*a2+a3*a3);
        s += __shfl_xor(s,16);  s += __shfl_xor(s,32);
        qq2 += __shfl_xor(qq2,16); qq2 += __shfl_xor(qq2,32);
        csum[ct]=s; csq[ct]=qq2;
        #pragma unroll
        for (int r=0;r<4;r++)
          u.cons.AhD[(wid*16 + quad*4 + r)*AP2 + ct*16 + ml] = f2bf1(acc[ct][r]);
      }
      #pragma unroll
      for (int jj=0;jj<2;jj++){
        int ct = quad*2 + jj, col = ct*16 + ml;
        atomicAdd(&u.cons.ssum[col], csum[ct]);
        atomicAdd(&u.cons.ssq[col],  csq[ct]);
      }
      // coalesced h1 write of own 16 rows (reads after same-wave D writes)
      {
        const uint4* s4 = (const uint4*)(u.cons.AhD + (wid*16 + ml)*AP2 + seg*32);
        uint4* dst = (uint4*)(h1 + ((size_t)q2*16 + ml)*128 + seg*32);
        dst[0]=s4[0]; dst[1]=s4[1]; dst[2]=s4[2]; dst[3]=s4[3];
      }
    }
    __syncthreads();
    int cp = (blk & 31)*256;
    if (tid < 128){ atomicAdd(&S1[cp+tid], u.cons.ssum[tid]); atomicAdd(&S1[cp+128+tid], u.cons.ssq[tid]); }
  }
}

// ---------- K6: GEMM2 bf16 MFMA + fused k-pool extrema, persistent: 4 tiles/block ----------
__global__ __launch_bounds__(256) void k_gemm2(const __hip_bfloat16* __restrict__ h1,
                                               const float* __restrict__ w2,
                                               const float* __restrict__ g1v, const float* __restrict__ b1v,
                                               const float* __restrict__ S1, float* __restrict__ S2,
                                               float* __restrict__ hmax, float* __restrict__ hmin){
  __shared__ __hip_bfloat16 Ah[64*AP2];
  __shared__ __hip_bfloat16 Bh[128*AP2];
  __shared__ float scb[128], shb[128], ssum[128], ssq[128];
  int tid = threadIdx.x;
  if (tid < 128){
    float s=0.f, q=0.f;
    for (int c=0;c<32;c++){ s += S1[c*256+tid]; q += S1[c*256+128+tid]; }
    float inv = 1.0f / (float)RTOT;
    float mean = s * inv;
    float var  = q * inv - mean*mean;
    float rs = 1.0f / sqrtf(var + 1e-5f);
    float scv = g1v[tid] * rs;
    scb[tid] = scv;
    shb[tid] = b1v[tid] - mean*scv;
    ssum[tid] = 0.f; ssq[tid] = 0.f;
  }
  {
    int o = tid >> 1, hf = tid & 1;
    const float4* wr = (const float4*)(w2 + (size_t)o*128 + hf*64);
    uint32_t* bd = (uint32_t*)(Bh + o*AP2 + hf*64);
    #pragma unroll
    for (int q=0;q<16;q++){
      float4 v = wr[q];
      bd[2*q]   = f2bf_pk(v.x, v.y);
      bd[2*q+1] = f2bf_pk(v.z, v.w);
    }
  }
  __syncthreads();
  int lane = tid & 63, wid = tid >> 6;
  int m0 = wid*16, ml = lane & 15, quad = lane >> 4;
  for (int j = 0; j < 4; j++){
    int tile = blockIdx.x*4 + j;
    int r0 = tile * 64;
    if (j) __syncthreads();
    {
      int row = tid >> 2, seg = tid & 3;
      const uint4* hp4 = (const uint4*)(h1 + ((size_t)(r0+row))*128 + seg*32);
      #pragma unroll
      for (int q=0;q<4;q++){
        uint4 u = hp4[q];
        int cg = seg*32 + q*8;
        uint32_t wv[4] = {u.x,u.y,u.z,u.w};
        uint32_t ov[4];
        #pragma unroll
        for (int t=0;t<4;t++){
          int c = cg + t*2;
          float a0 = fmaxf(fmaf(bflo(wv[t]), scb[c],   shb[c]),   0.f);
          float a1 = fmaxf(fmaf(bfhi(wv[t]), scb[c+1], shb[c+1]), 0.f);
          ov[t] = f2bf_pk(a0, a1);
        }
        *(uint4*)(Ah + row*AP2 + cg) = make_uint4(ov[0],ov[1],ov[2],ov[3]);
      }
    }
    __syncthreads();
    short8v af[4];
    #pragma unroll
    for (int kc=0;kc<4;kc++)
      af[kc] = *(const short8v*)(Ah + (m0+ml)*AP2 + kc*32 + quad*8);
    floatx4 acc[8];
    #pragma unroll
    for (int ct=0;ct<8;ct++) acc[ct] = (floatx4){0.f,0.f,0.f,0.f};
    #pragma unroll
    for (int ct=0;ct<8;ct++){
      #pragma unroll
      for (int kc=0;kc<4;kc++){
        short8v bf = *(const short8v*)(Bh + (ct*16+ml)*AP2 + kc*32 + quad*8);
        acc[ct] = __builtin_amdgcn_mfma_f32_16x16x32_bf16(af[kc], bf, acc[ct], 0, 0, 0);
      }
    }
    int mrow = (r0 >> 4) + wid;
    float cm[8], cn[8], cs[8], cq[8];
    #pragma unroll
    for (int ct=0;ct<8;ct++){
      float a0=acc[ct][0], a1=acc[ct][1], a2=acc[ct][2], a3=acc[ct][3];
      float mx = fmaxf(fmaxf(a0,a1), fmaxf(a2,a3));
      float mn = fminf(fminf(a0,a1), fminf(a2,a3));
      float s  = (a0+a1)+(a2+a3);
      float q2 = (a0*a0+a1*a1)+(a2*a2+a3*a3);
      mx = fmaxf(mx, __shfl_xor(mx,16)); mx = fmaxf(mx, __shfl_xor(mx,32));
      mn = fminf(mn, __shfl_xor(mn,16)); mn = fminf(mn, __shfl_xor(mn,32));
      s += __shfl_xor(s,16);  s += __shfl_xor(s,32);
      q2 += __shfl_xor(q2,16); q2 += __shfl_xor(q2,32);
      cm[ct]=mx; cn[ct]=mn; cs[ct]=s; cq[ct]=q2;
    }
    #pragma unroll
    for (int jj=0;jj<2;jj++){
      int ct = quad*2 + jj, col = ct*16 + ml;
      hmax[(size_t)mrow*128 + col] = cm[ct];
      hmin[(size_t)mrow*128 + col] = cn[ct];
      atomicAdd(&ssum[col], cs[ct]);
      atomicAdd(&ssq[col],  cq[ct]);
    }
  }
  __syncthreads();
  int cp = (blockIdx.x & 31)*256;
  if (tid < 128){ atomicAdd(&S2[cp+tid], ssum[tid]); atomicAdd(&S2[cp+128+tid], ssq[tid]); }
}

// ---------- K8: bn2+relu on pooled extrema (P2 computed per-block from S2) ----------
__global__ __launch_bounds__(256) void k_pool(const float* __restrict__ hmax, const float* __restrict__ hmin,
                                              const float* __restrict__ g2v, const float* __restrict__ b2v,
                                              const float* __restrict__ S2, float* __restrict__ out1){
  __shared__ float ot[128*65];
  __shared__ float scs[128], shs[128];
  int tid = threadIdx.x, blk = blockIdx.x;
  int b = blk >> 4, m0 = (blk & 15) * 64;
  if (tid < 128){
    float s=0.f, q=0.f;
    for (int c=0;c<32;c++){ s += S2[c*256+tid]; q += S2[c*256+128+tid]; }
    float inv = 1.0f / (float)RTOT;
    float mean = s * inv;
    float var  = q * inv - mean*mean;
    float rs = 1.0f / sqrtf(var + 1e-5f);
    float scv = g2v[tid] * rs;
    scs[tid] = scv;
    shs[tid] = b2v[tid] - mean*scv;
  }
  __syncthreads();
  int ml = tid >> 2, oq = tid & 3, o0 = oq*32;
  int gm = b*MM + m0 + ml;
  const float4* xr = (const float4*)(hmax + (size_t)gm*128 + o0);
  const float4* nr = (const float4*)(hmin + (size_t)gm*128 + o0);
  #pragma unroll
  for (int j2=0;j2<8;j2++){
    float4 hx = xr[j2], hn = nr[j2];
    float hv[4] = {hx.x, hx.y, hx.z, hx.w};
    float nv[4] = {hn.x, hn.y, hn.z, hn.w};
    #pragma unroll
    for (int e=0;e<4;e++){
      int c = o0 + j2*4 + e;
      float sc = scs[c], sh = shs[c];
      float h = (sc >= 0.f) ? hv[e] : nv[e];
      ot[c*65 + ml] = fmaxf(fmaf(h, sc, sh), 0.f);
    }
  }
  __syncthreads();
  int o = tid >> 1, mh = tid & 1;
  float* dst = out1 + ((size_t)(b*COUT + o))*MM + m0 + mh*32;
  #pragma unroll
  for (int j2=0;j2<8;j2++){
    float4 v;
    v.x=ot[o*65+mh*32+j2*4+0]; v.y=ot[o*65+mh*32+j2*4+1];
    v.z=ot[o*65+mh*32+j2*4+2]; v.w=ot[o*65+mh*32+j2*4+3];
    *(float4*)(dst + j2*4) = v;
  }
}

extern "C" void kernel_launch(void* const* d_in, const int* in_sizes, int n_in,
                              void* d_out, int out_size, void* d_ws, size_t ws_size,
                              hipStream_t stream) {
  (void)in_sizes; (void)n_in; (void)out_size; (void)ws_size;
  const float* p1 = (const float*)d_in[0];
  const float* x1 = (const float*)d_in[1];
  const float* w1 = (const float*)d_in[2];
  const float* g1 = (const float*)d_in[3];
  const float* b1 = (const float*)d_in[4];
  const float* w2 = (const float*)d_in[5];
  const float* g2 = (const float*)d_in[6];
  const float* b2 = (const float*)d_in[7];
  float* out = (float*)d_out;
  float* ws  = (float*)d_ws;

  // ws map (float indices)
  uint16_t* xtb = (uint16_t*)ws;                    // [B,N,64] bf16
  float4* p1n   = (float4*)(ws + 2097152);          // [B,N]
  float*  p2w   = ws + 2621440;                     // [B,M,4]
  float*  S1    = ws + 2686976;                     // 8192
  float*  S2    = ws + 2695168;                     // 8192
  uint16_t* h1  = (uint16_t*)(ws + 2703872);        // [R,128] bf16
  float*  hmax  = ws + 19481088;                    // [B*M,128]
  float*  hmin  = ws + 21578240;                    // [B*M,128]
  int*    prog  = (int*)(ws + 23675392);            // 16 batches x stride 16
  int*    prep_done = (int*)(ws + 23675392) + 256;
  float*  outp2 = out;                              // [B,M,3]
  float*  out1  = out + 49152;                      // [B,128,M]

  hipMemsetAsync(prog, 0, 2048, stream);            // prog + prep_done

  // Regular launch: 256 blocks x 82KB LDS -> 1 block/CU on 256 CUs, all blocks
  // co-resident at dispatch (cooperative semantics not needed; saves coop overhead).
  k_pre2<<<256, 512, 0, stream>>>(p1, x1, w1, outp2, p2w, p1n, xtb, S1,
                                  h1, S1, prog, prep_done);

  k_gemm2<<<1024, 256, 0, stream>>>((const __hip_bfloat16*)h1, w2, g1, b1, S1, S2, hmax, hmin);
  k_pool<<<256, 256, 0, stream>>>(hmax, hmin, g2, b2, S2, out1);
}